// Round 1
// baseline (743.854 us; speedup 1.0000x reference)
//
#include <hip/hip_runtime.h>
#include <math.h>

#define Bn   128          // B' = 8*2048*512 / (512*128)
#define Ech  512          // E
#define Dd   128          // D
#define NCNT 16384        // Bn * Dd  (BatchNorm reduction count)

__device__ __forceinline__ float gelu_exact(float x) {
    return 0.5f * x * (1.0f + erff(x * 0.70710678118654752f));
}

// ---------------------------------------------------------------------------
// k1: grouped conv1d (k=3, pad=1, groups=128) + bias + residual + GELU,
//     store q_pre, accumulate per-channel sum/sumsq for BatchNorm.
// grid (8 channel-chunks of 64, 128 n), block 256
// ---------------------------------------------------------------------------
__global__ __launch_bounds__(256) void k_conv_gelu_stats(
    const float* __restrict__ x, const float* __restrict__ cw,
    const float* __restrict__ cb, float* __restrict__ qpre,
    float* __restrict__ csum, float* __restrict__ csumsq)
{
    __shared__ float xt[64 * 128];
    const int n  = blockIdx.y;
    const int c0 = blockIdx.x * 64;
    const float* xb = x + (size_t)n * Ech * Dd + (size_t)c0 * Dd;

    const float4* xb4 = (const float4*)xb;
    float4* xt4 = (float4*)xt;
    #pragma unroll
    for (int j = 0; j < 8; j++) xt4[threadIdx.x + 256 * j] = xb4[threadIdx.x + 256 * j];
    __syncthreads();

    const int oloc = threadIdx.x >> 2;       // 0..63 output channel (local)
    const int hq   = threadIdx.x & 3;
    const int o    = c0 + oloc;              // global channel
    const int gb   = oloc & ~3;              // input-group base (local)

    float w[4][3];
    #pragma unroll
    for (int i = 0; i < 4; i++)
        #pragma unroll
        for (int kk = 0; kk < 3; kk++) w[i][kk] = cw[o * 12 + i * 3 + kk];
    const float bias = cb[o];

    float s = 0.f, ss = 0.f;
    float* qrow = qpre + (size_t)n * Ech * Dd + (size_t)o * Dd;
    #pragma unroll 4
    for (int j = 0; j < 32; j++) {
        const int h = hq + 4 * j;
        float acc = bias;
        #pragma unroll
        for (int i = 0; i < 4; i++) {
            const float* row = &xt[(gb + i) * 128];
            const float xm = (h > 0)   ? row[h - 1] : 0.f;
            const float xc = row[h];
            const float xp = (h < 127) ? row[h + 1] : 0.f;
            acc = fmaf(xm, w[i][0], acc);
            acc = fmaf(xc, w[i][1], acc);
            acc = fmaf(xp, w[i][2], acc);
        }
        acc += xt[oloc * 128 + h];           // residual
        const float g = gelu_exact(acc);
        qrow[h] = g;
        s += g; ss = fmaf(g, g, ss);
    }
    // threads 4o..4o+3 are adjacent lanes: butterfly over 2 bits
    s  += __shfl_xor(s, 1);  s  += __shfl_xor(s, 2);
    ss += __shfl_xor(ss, 1); ss += __shfl_xor(ss, 2);
    if (hq == 0) { atomicAdd(&csum[o], s); atomicAdd(&csumsq[o], ss); }
}

// ---------------------------------------------------------------------------
// k2: finalize BN stats -> per-channel scale/shift
// ---------------------------------------------------------------------------
__global__ void k_stats_final(const float* __restrict__ csum,
                              const float* __restrict__ csumsq,
                              const float* __restrict__ gamma,
                              const float* __restrict__ beta,
                              float* __restrict__ scale, float* __restrict__ shift)
{
    const int c = threadIdx.x;
    if (c < Ech) {
        const float mu   = csum[c]   * (1.0f / NCNT);
        const float var  = csumsq[c] * (1.0f / NCNT) - mu * mu;
        const float rstd = rsqrtf(var + 1e-5f);
        const float sc   = gamma[c] * rstd;
        scale[c] = sc;
        shift[c] = beta[c] - mu * sc;
    }
}

// ---------------------------------------------------------------------------
// k3: k = gelu(softmax(x, axis=E)); one thread per (n,d) column.
// grid 64, block 256 (2 n per block)
// ---------------------------------------------------------------------------
__global__ __launch_bounds__(256) void k_softmax_e_gelu(
    const float* __restrict__ x, float* __restrict__ kout)
{
    const int d = threadIdx.x & 127;
    const int n = blockIdx.x * 2 + (threadIdx.x >> 7);
    const float* xb = x + (size_t)n * Ech * Dd + d;
    float m = -1e30f;
    #pragma unroll 8
    for (int e = 0; e < Ech; e++) m = fmaxf(m, xb[e * Dd]);
    float sum = 0.f;
    #pragma unroll 8
    for (int e = 0; e < Ech; e++) sum += __expf(xb[e * Dd] - m);
    const float inv = 1.0f / sum;
    float* kb = kout + (size_t)n * Ech * Dd + d;
    #pragma unroll 8
    for (int e = 0; e < Ech; e++) kb[e * Dd] = gelu_exact(__expf(xb[e * Dd] - m) * inv);
}

// ---------------------------------------------------------------------------
// fp32 tiled GEMM micro-kernel helpers (64x64 tile, 4x4 microtile, K-major LDS)
// ---------------------------------------------------------------------------
#define LDSPAD 68

__device__ __forceinline__ void micro_fma(const float (*As)[LDSPAD],
                                          const float (*Bs)[LDSPAD],
                                          int r, int c, float acc[4][4])
{
    #pragma unroll
    for (int kk = 0; kk < 32; kk++) {
        const float4 a = *(const float4*)&As[kk][r];
        const float4 b = *(const float4*)&Bs[kk][c];
        const float av[4] = {a.x, a.y, a.z, a.w};
        const float bv[4] = {b.x, b.y, b.z, b.w};
        #pragma unroll
        for (int i = 0; i < 4; i++)
            #pragma unroll
            for (int j = 0; j < 4; j++)
                acc[i][j] = fmaf(av[i], bv[j], acc[i][j]);
    }
}

// ---------------------------------------------------------------------------
// k_qk: S[n,e,f] = (q . k) / sqrt(512);  q = qpre*scale[e]+shift[e] (BN fused)
// A,B both row-major with contiguous K=128. grid (8,8,128), block 256
// ---------------------------------------------------------------------------
__global__ __launch_bounds__(256) void k_qk(
    const float* __restrict__ qpre, const float* __restrict__ scale,
    const float* __restrict__ shift, const float* __restrict__ kbuf,
    float* __restrict__ attn)
{
    __shared__ float As[32][LDSPAD];
    __shared__ float Bs[32][LDSPAD];
    const int n = blockIdx.z;
    const int e0 = blockIdx.x * 64, f0 = blockIdx.y * 64;
    const int t = threadIdx.x;
    const int tx = t & 15, ty = t >> 4;
    const int r = ty * 4, c = tx * 4;
    float acc[4][4] = {};

    const float* qb = qpre + (size_t)n * Ech * Dd + (size_t)e0 * Dd;
    const float* kb = kbuf + (size_t)n * Ech * Dd + (size_t)f0 * Dd;

    for (int kc = 0; kc < 128; kc += 32) {
        #pragma unroll
        for (int p = 0; p < 2; p++) {
            const int idx4 = t + 256 * p;        // 0..511
            const int row  = idx4 >> 3;          // 8 float4 per 32-wide row
            const int k4   = (idx4 & 7) * 4;
            float4 a = *(const float4*)(qb + row * Dd + kc + k4);
            const float sc = scale[e0 + row], sh = shift[e0 + row];
            As[k4 + 0][row] = fmaf(a.x, sc, sh);
            As[k4 + 1][row] = fmaf(a.y, sc, sh);
            As[k4 + 2][row] = fmaf(a.z, sc, sh);
            As[k4 + 3][row] = fmaf(a.w, sc, sh);
            float4 b = *(const float4*)(kb + row * Dd + kc + k4);
            Bs[k4 + 0][row] = b.x;
            Bs[k4 + 1][row] = b.y;
            Bs[k4 + 2][row] = b.z;
            Bs[k4 + 3][row] = b.w;
        }
        __syncthreads();
        micro_fma(As, Bs, r, c, acc);
        __syncthreads();
    }
    const float rsc = 0.044194173824159216f;     // 1/sqrt(512)
    float* ab = attn + (size_t)n * Ech * Ech + (size_t)e0 * Ech + f0;
    #pragma unroll
    for (int i = 0; i < 4; i++) {
        float4 o = {acc[i][0] * rsc, acc[i][1] * rsc, acc[i][2] * rsc, acc[i][3] * rsc};
        *(float4*)(ab + (size_t)(r + i) * Ech + c) = o;
    }
}

// ---------------------------------------------------------------------------
// k_rowsoftmax: softmax over last dim (512) of attn, in place.
// one wave per row, 4 rows/block. grid 16384, block 256
// ---------------------------------------------------------------------------
__global__ __launch_bounds__(256) void k_rowsoftmax(float* __restrict__ attn)
{
    const int row  = blockIdx.x * 4 + (threadIdx.x >> 6);
    const int lane = threadIdx.x & 63;
    float* rp = attn + (size_t)row * Ech;
    float4 v1 = *(float4*)(rp + lane * 4);
    float4 v2 = *(float4*)(rp + 256 + lane * 4);
    float m = fmaxf(fmaxf(fmaxf(v1.x, v1.y), fmaxf(v1.z, v1.w)),
                    fmaxf(fmaxf(v2.x, v2.y), fmaxf(v2.z, v2.w)));
    #pragma unroll
    for (int off = 32; off >= 1; off >>= 1) m = fmaxf(m, __shfl_xor(m, off));
    v1.x = __expf(v1.x - m); v1.y = __expf(v1.y - m);
    v1.z = __expf(v1.z - m); v1.w = __expf(v1.w - m);
    v2.x = __expf(v2.x - m); v2.y = __expf(v2.y - m);
    v2.z = __expf(v2.z - m); v2.w = __expf(v2.w - m);
    float s = v1.x + v1.y + v1.z + v1.w + v2.x + v2.y + v2.z + v2.w;
    #pragma unroll
    for (int off = 32; off >= 1; off >>= 1) s += __shfl_xor(s, off);
    const float inv = 1.0f / s;
    v1.x *= inv; v1.y *= inv; v1.z *= inv; v1.w *= inv;
    v2.x *= inv; v2.y *= inv; v2.z *= inv; v2.w *= inv;
    *(float4*)(rp + lane * 4) = v1;
    *(float4*)(rp + 256 + lane * 4) = v2;
}

// ---------------------------------------------------------------------------
// k_vgemm: v[n,e,o] = gelu( sum_d x[n,e,d]*lw[o,d] + lb[o] )
// A=x rows (K contig), B=lw rows (K contig). grid (8,2,128), block 256
// ---------------------------------------------------------------------------
__global__ __launch_bounds__(256) void k_vgemm(
    const float* __restrict__ x, const float* __restrict__ lw,
    const float* __restrict__ lb, float* __restrict__ v)
{
    __shared__ float As[32][LDSPAD];
    __shared__ float Bs[32][LDSPAD];
    const int n = blockIdx.z;
    const int e0 = blockIdx.x * 64, o0 = blockIdx.y * 64;
    const int t = threadIdx.x;
    const int tx = t & 15, ty = t >> 4;
    const int r = ty * 4, c = tx * 4;
    float acc[4][4] = {};

    const float* xb = x  + (size_t)n * Ech * Dd + (size_t)e0 * Dd;
    const float* wb = lw + (size_t)o0 * Dd;

    for (int kc = 0; kc < 128; kc += 32) {
        #pragma unroll
        for (int p = 0; p < 2; p++) {
            const int idx4 = t + 256 * p;
            const int row  = idx4 >> 3;
            const int k4   = (idx4 & 7) * 4;
            float4 a = *(const float4*)(xb + row * Dd + kc + k4);
            As[k4 + 0][row] = a.x;
            As[k4 + 1][row] = a.y;
            As[k4 + 2][row] = a.z;
            As[k4 + 3][row] = a.w;
            float4 b = *(const float4*)(wb + row * Dd + kc + k4);
            Bs[k4 + 0][row] = b.x;
            Bs[k4 + 1][row] = b.y;
            Bs[k4 + 2][row] = b.z;
            Bs[k4 + 3][row] = b.w;
        }
        __syncthreads();
        micro_fma(As, Bs, r, c, acc);
        __syncthreads();
    }
    float* vb = v + (size_t)n * Ech * Dd + (size_t)e0 * Dd + o0;
    #pragma unroll
    for (int i = 0; i < 4; i++) {
        float4 o;
        o.x = gelu_exact(acc[i][0] + lb[o0 + c + 0]);
        o.y = gelu_exact(acc[i][1] + lb[o0 + c + 1]);
        o.z = gelu_exact(acc[i][2] + lb[o0 + c + 2]);
        o.w = gelu_exact(acc[i][3] + lb[o0 + c + 3]);
        *(float4*)(vb + (size_t)(r + i) * Dd + c) = o;
    }
}

// ---------------------------------------------------------------------------
// k_outgemm: out[n,e,d] = sum_f attn[n,e,f] * v[n,f,d]
// A=attn rows (K contig), B=v [K][N] natural. grid (8,2,128), block 256
// ---------------------------------------------------------------------------
__global__ __launch_bounds__(256) void k_outgemm(
    const float* __restrict__ attn, const float* __restrict__ v,
    float* __restrict__ out)
{
    __shared__ float As[32][LDSPAD];
    __shared__ float Bs[32][LDSPAD];
    const int n = blockIdx.z;
    const int e0 = blockIdx.x * 64, d0 = blockIdx.y * 64;
    const int t = threadIdx.x;
    const int tx = t & 15, ty = t >> 4;
    const int r = ty * 4, c = tx * 4;
    float acc[4][4] = {};

    const float* ab = attn + (size_t)n * Ech * Ech + (size_t)e0 * Ech;
    const float* vb = v    + (size_t)n * Ech * Dd + d0;

    for (int kc = 0; kc < 512; kc += 32) {
        #pragma unroll
        for (int p = 0; p < 2; p++) {
            const int idx4 = t + 256 * p;
            // A: 64 rows x 32 k
            const int arow = idx4 >> 3;
            const int ak4  = (idx4 & 7) * 4;
            float4 a = *(const float4*)(ab + (size_t)arow * Ech + kc + ak4);
            As[ak4 + 0][arow] = a.x;
            As[ak4 + 1][arow] = a.y;
            As[ak4 + 2][arow] = a.z;
            As[ak4 + 3][arow] = a.w;
            // B: 32 rows(f) x 64 d, natural K-major
            const int bk  = idx4 >> 4;           // 16 float4 per row
            const int bd4 = (idx4 & 15) * 4;
            float4 b = *(const float4*)(vb + (size_t)(kc + bk) * Dd + bd4);
            *(float4*)&Bs[bk][bd4] = b;
        }
        __syncthreads();
        micro_fma(As, Bs, r, c, acc);
        __syncthreads();
    }
    float* ob = out + (size_t)n * Ech * Dd + (size_t)e0 * Dd + d0;
    #pragma unroll
    for (int i = 0; i < 4; i++) {
        float4 o = {acc[i][0], acc[i][1], acc[i][2], acc[i][3]};
        *(float4*)(ob + (size_t)(r + i) * Dd + c) = o;
    }
}

// ---------------------------------------------------------------------------
extern "C" void kernel_launch(void* const* d_in, const int* in_sizes, int n_in,
                              void* d_out, int out_size, void* d_ws, size_t ws_size,
                              hipStream_t stream)
{
    const float* x     = (const float*)d_in[0];   // (8,2048,512) == (128,512,128)
    const float* cw    = (const float*)d_in[1];   // (512,4,3)
    const float* cb    = (const float*)d_in[2];   // (512,)
    const float* gamma = (const float*)d_in[3];   // (512,)
    const float* beta  = (const float*)d_in[4];   // (512,)
    const float* lw    = (const float*)d_in[5];   // (128,128)
    const float* lb    = (const float*)d_in[6];   // (128,)

    float* out  = (float*)d_out;                  // 8388608 floats
    float* attn = out + (size_t)8388608;          // 33554432 floats

    float* qpre   = (float*)d_ws;                 // 8388608 floats
    float* kbuf   = qpre + 8388608;               // 8388608 floats
    float* vbuf   = qpre;                         // reuse: q_pre dead after k_qk
    float* csum   = kbuf + 8388608;
    float* csumsq = csum + 512;
    float* scale  = csumsq + 512;
    float* shift  = scale + 512;

    hipMemsetAsync(csum, 0, 2 * 512 * sizeof(float), stream);

    k_conv_gelu_stats<<<dim3(8, 128), 256, 0, stream>>>(x, cw, cb, qpre, csum, csumsq);
    k_stats_final<<<1, 512, 0, stream>>>(csum, csumsq, gamma, beta, scale, shift);
    k_softmax_e_gelu<<<64, 256, 0, stream>>>(x, kbuf);
    k_qk<<<dim3(8, 8, 128), 256, 0, stream>>>(qpre, scale, shift, kbuf, attn);
    k_rowsoftmax<<<16384, 256, 0, stream>>>(attn);
    k_vgemm<<<dim3(8, 2, 128), 256, 0, stream>>>(x, lw, lb, vbuf);
    k_outgemm<<<dim3(8, 2, 128), 256, 0, stream>>>(attn, vbuf, out);
}

// Round 2
// 522.035 us; speedup vs baseline: 1.4249x; 1.4249x over previous
//
#include <hip/hip_runtime.h>
#include <math.h>

#define Bn   128          // B' = 8*2048*512 / (512*128)
#define Ech  512          // E
#define Dd   128          // D
#define NCNT 16384        // Bn * Dd  (BatchNorm reduction count)

__device__ __forceinline__ float gelu_exact(float x) {
    return 0.5f * x * (1.0f + erff(x * 0.70710678118654752f));
}

// ---------------------------------------------------------------------------
// k1: grouped conv1d (k=3, pad=1, groups=128) + bias + residual + GELU,
//     store q_pre, accumulate per-channel sum/sumsq for BatchNorm.
// grid (8 channel-chunks of 64, 128 n), block 256
// ---------------------------------------------------------------------------
__global__ __launch_bounds__(256) void k_conv_gelu_stats(
    const float* __restrict__ x, const float* __restrict__ cw,
    const float* __restrict__ cb, float* __restrict__ qpre,
    float* __restrict__ csum, float* __restrict__ csumsq)
{
    __shared__ float xt[64 * 128];
    const int n  = blockIdx.y;
    const int c0 = blockIdx.x * 64;
    const float* xb = x + (size_t)n * Ech * Dd + (size_t)c0 * Dd;

    const float4* xb4 = (const float4*)xb;
    float4* xt4 = (float4*)xt;
    #pragma unroll
    for (int j = 0; j < 8; j++) xt4[threadIdx.x + 256 * j] = xb4[threadIdx.x + 256 * j];
    __syncthreads();

    const int oloc = threadIdx.x >> 2;       // 0..63 output channel (local)
    const int hq   = threadIdx.x & 3;
    const int o    = c0 + oloc;              // global channel
    const int gb   = oloc & ~3;              // input-group base (local)

    float w[4][3];
    #pragma unroll
    for (int i = 0; i < 4; i++)
        #pragma unroll
        for (int kk = 0; kk < 3; kk++) w[i][kk] = cw[o * 12 + i * 3 + kk];
    const float bias = cb[o];

    float s = 0.f, ss = 0.f;
    float* qrow = qpre + (size_t)n * Ech * Dd + (size_t)o * Dd;
    #pragma unroll 4
    for (int j = 0; j < 32; j++) {
        const int h = hq + 4 * j;
        float acc = bias;
        #pragma unroll
        for (int i = 0; i < 4; i++) {
            const float* row = &xt[(gb + i) * 128];
            const float xm = (h > 0)   ? row[h - 1] : 0.f;
            const float xc = row[h];
            const float xp = (h < 127) ? row[h + 1] : 0.f;
            acc = fmaf(xm, w[i][0], acc);
            acc = fmaf(xc, w[i][1], acc);
            acc = fmaf(xp, w[i][2], acc);
        }
        acc += xt[oloc * 128 + h];           // residual
        const float g = gelu_exact(acc);
        qrow[h] = g;
        s += g; ss = fmaf(g, g, ss);
    }
    // threads 4o..4o+3 are adjacent lanes: butterfly over 2 bits
    s  += __shfl_xor(s, 1);  s  += __shfl_xor(s, 2);
    ss += __shfl_xor(ss, 1); ss += __shfl_xor(ss, 2);
    if (hq == 0) { atomicAdd(&csum[o], s); atomicAdd(&csumsq[o], ss); }
}

// ---------------------------------------------------------------------------
// k2: finalize BN stats -> per-channel scale/shift
// ---------------------------------------------------------------------------
__global__ void k_stats_final(const float* __restrict__ csum,
                              const float* __restrict__ csumsq,
                              const float* __restrict__ gamma,
                              const float* __restrict__ beta,
                              float* __restrict__ scale, float* __restrict__ shift)
{
    const int c = threadIdx.x;
    if (c < Ech) {
        const float mu   = csum[c]   * (1.0f / NCNT);
        const float var  = csumsq[c] * (1.0f / NCNT) - mu * mu;
        const float rstd = rsqrtf(var + 1e-5f);
        const float sc   = gamma[c] * rstd;
        scale[c] = sc;
        shift[c] = beta[c] - mu * sc;
    }
}

// ---------------------------------------------------------------------------
// k3 v2: k = gelu(softmax(x, axis=E)), register-cached single-read-pass.
// Block owns (n, d-quarter): 32 d-columns x 512 e. 256 threads:
//   d4 = t&7 (float4 column), eg = t>>3 (e-group 0..31), e = eg + 32*j.
// Each thread holds 16 float4 in regs; LDS tree-reduce (32 e-groups) for
// per-column max and sum. grid (4,128), block 256.
// ---------------------------------------------------------------------------
__global__ __launch_bounds__(256) void k_softmax_e_gelu_v2(
    const float* __restrict__ x, float* __restrict__ kout)
{
    __shared__ float4 red[32][8];
    const int n  = blockIdx.y;
    const int qd = blockIdx.x;           // d-quarter
    const int t  = threadIdx.x;
    const int d4 = t & 7;                // local float4-column
    const int eg = t >> 3;               // 0..31
    const float* xb = x + (size_t)n * Ech * Dd + qd * 32 + d4 * 4;

    float4 vb[16];
    float4 m4 = {-3e38f, -3e38f, -3e38f, -3e38f};
    #pragma unroll
    for (int j = 0; j < 16; j++) {
        const int e = eg + 32 * j;
        float4 v = *(const float4*)(xb + (size_t)e * Dd);
        vb[j] = v;
        m4.x = fmaxf(m4.x, v.x); m4.y = fmaxf(m4.y, v.y);
        m4.z = fmaxf(m4.z, v.z); m4.w = fmaxf(m4.w, v.w);
    }
    red[eg][d4] = m4;
    __syncthreads();
    #pragma unroll
    for (int s = 16; s >= 1; s >>= 1) {
        if (eg < s) {
            float4 a = red[eg][d4], b = red[eg + s][d4];
            a.x = fmaxf(a.x, b.x); a.y = fmaxf(a.y, b.y);
            a.z = fmaxf(a.z, b.z); a.w = fmaxf(a.w, b.w);
            red[eg][d4] = a;
        }
        __syncthreads();
    }
    m4 = red[0][d4];
    __syncthreads();

    float4 s4 = {0.f, 0.f, 0.f, 0.f};
    #pragma unroll
    for (int j = 0; j < 16; j++) {
        float4 v = vb[j];
        v.x = __expf(v.x - m4.x); v.y = __expf(v.y - m4.y);
        v.z = __expf(v.z - m4.z); v.w = __expf(v.w - m4.w);
        vb[j] = v;
        s4.x += v.x; s4.y += v.y; s4.z += v.z; s4.w += v.w;
    }
    red[eg][d4] = s4;
    __syncthreads();
    #pragma unroll
    for (int s = 16; s >= 1; s >>= 1) {
        if (eg < s) {
            float4 a = red[eg][d4], b = red[eg + s][d4];
            a.x += b.x; a.y += b.y; a.z += b.z; a.w += b.w;
            red[eg][d4] = a;
        }
        __syncthreads();
    }
    s4 = red[0][d4];
    const float4 inv4 = {1.0f / s4.x, 1.0f / s4.y, 1.0f / s4.z, 1.0f / s4.w};

    float* kb = kout + (size_t)n * Ech * Dd + qd * 32 + d4 * 4;
    #pragma unroll
    for (int j = 0; j < 16; j++) {
        const int e = eg + 32 * j;
        float4 p = vb[j];
        float4 o;
        o.x = gelu_exact(p.x * inv4.x);
        o.y = gelu_exact(p.y * inv4.y);
        o.z = gelu_exact(p.z * inv4.z);
        o.w = gelu_exact(p.w * inv4.w);
        *(float4*)(kb + (size_t)e * Dd) = o;
    }
}

// ---------------------------------------------------------------------------
// fp32 tiled GEMM micro-kernel helpers (64x64 tile, 4x4 microtile, K-major LDS)
// ---------------------------------------------------------------------------
#define LDSPAD 68

__device__ __forceinline__ void micro_fma(const float (*As)[LDSPAD],
                                          const float (*Bs)[LDSPAD],
                                          int r, int c, float acc[4][4])
{
    #pragma unroll
    for (int kk = 0; kk < 32; kk++) {
        const float4 a = *(const float4*)&As[kk][r];
        const float4 b = *(const float4*)&Bs[kk][c];
        const float av[4] = {a.x, a.y, a.z, a.w};
        const float bv[4] = {b.x, b.y, b.z, b.w};
        #pragma unroll
        for (int i = 0; i < 4; i++)
            #pragma unroll
            for (int j = 0; j < 4; j++)
                acc[i][j] = fmaf(av[i], bv[j], acc[i][j]);
    }
}

// ---------------------------------------------------------------------------
// k_qk: S[n,e,f] = (q . k) / sqrt(512);  q = qpre*scale[e]+shift[e] (BN fused)
// A,B both row-major with contiguous K=128. grid (8,8,128), block 256
// ---------------------------------------------------------------------------
__global__ __launch_bounds__(256) void k_qk(
    const float* __restrict__ qpre, const float* __restrict__ scale,
    const float* __restrict__ shift, const float* __restrict__ kbuf,
    float* __restrict__ attn)
{
    __shared__ float As[32][LDSPAD];
    __shared__ float Bs[32][LDSPAD];
    const int n = blockIdx.z;
    const int e0 = blockIdx.x * 64, f0 = blockIdx.y * 64;
    const int t = threadIdx.x;
    const int tx = t & 15, ty = t >> 4;
    const int r = ty * 4, c = tx * 4;
    float acc[4][4] = {};

    const float* qb = qpre + (size_t)n * Ech * Dd + (size_t)e0 * Dd;
    const float* kb = kbuf + (size_t)n * Ech * Dd + (size_t)f0 * Dd;

    for (int kc = 0; kc < 128; kc += 32) {
        #pragma unroll
        for (int p = 0; p < 2; p++) {
            const int idx4 = t + 256 * p;        // 0..511
            const int row  = idx4 >> 3;          // 8 float4 per 32-wide row
            const int k4   = (idx4 & 7) * 4;
            float4 a = *(const float4*)(qb + row * Dd + kc + k4);
            const float sc = scale[e0 + row], sh = shift[e0 + row];
            As[k4 + 0][row] = fmaf(a.x, sc, sh);
            As[k4 + 1][row] = fmaf(a.y, sc, sh);
            As[k4 + 2][row] = fmaf(a.z, sc, sh);
            As[k4 + 3][row] = fmaf(a.w, sc, sh);
            float4 b = *(const float4*)(kb + row * Dd + kc + k4);
            Bs[k4 + 0][row] = b.x;
            Bs[k4 + 1][row] = b.y;
            Bs[k4 + 2][row] = b.z;
            Bs[k4 + 3][row] = b.w;
        }
        __syncthreads();
        micro_fma(As, Bs, r, c, acc);
        __syncthreads();
    }
    const float rsc = 0.044194173824159216f;     // 1/sqrt(512)
    float* ab = attn + (size_t)n * Ech * Ech + (size_t)e0 * Ech + f0;
    #pragma unroll
    for (int i = 0; i < 4; i++) {
        float4 o = {acc[i][0] * rsc, acc[i][1] * rsc, acc[i][2] * rsc, acc[i][3] * rsc};
        *(float4*)(ab + (size_t)(r + i) * Ech + c) = o;
    }
}

// ---------------------------------------------------------------------------
// k_rowsoftmax: softmax over last dim (512) of attn, in place.
// one wave per row, 4 rows/block. grid 16384, block 256
// ---------------------------------------------------------------------------
__global__ __launch_bounds__(256) void k_rowsoftmax(float* __restrict__ attn)
{
    const int row  = blockIdx.x * 4 + (threadIdx.x >> 6);
    const int lane = threadIdx.x & 63;
    float* rp = attn + (size_t)row * Ech;
    float4 v1 = *(float4*)(rp + lane * 4);
    float4 v2 = *(float4*)(rp + 256 + lane * 4);
    float m = fmaxf(fmaxf(fmaxf(v1.x, v1.y), fmaxf(v1.z, v1.w)),
                    fmaxf(fmaxf(v2.x, v2.y), fmaxf(v2.z, v2.w)));
    #pragma unroll
    for (int off = 32; off >= 1; off >>= 1) m = fmaxf(m, __shfl_xor(m, off));
    v1.x = __expf(v1.x - m); v1.y = __expf(v1.y - m);
    v1.z = __expf(v1.z - m); v1.w = __expf(v1.w - m);
    v2.x = __expf(v2.x - m); v2.y = __expf(v2.y - m);
    v2.z = __expf(v2.z - m); v2.w = __expf(v2.w - m);
    float s = v1.x + v1.y + v1.z + v1.w + v2.x + v2.y + v2.z + v2.w;
    #pragma unroll
    for (int off = 32; off >= 1; off >>= 1) s += __shfl_xor(s, off);
    const float inv = 1.0f / s;
    v1.x *= inv; v1.y *= inv; v1.z *= inv; v1.w *= inv;
    v2.x *= inv; v2.y *= inv; v2.z *= inv; v2.w *= inv;
    *(float4*)(rp + lane * 4) = v1;
    *(float4*)(rp + 256 + lane * 4) = v2;
}

// ---------------------------------------------------------------------------
// k_vgemm: v[n,e,o] = gelu( sum_d x[n,e,d]*lw[o,d] + lb[o] )
// A=x rows (K contig), B=lw rows (K contig). grid (8,2,128), block 256
// ---------------------------------------------------------------------------
__global__ __launch_bounds__(256) void k_vgemm(
    const float* __restrict__ x, const float* __restrict__ lw,
    const float* __restrict__ lb, float* __restrict__ v)
{
    __shared__ float As[32][LDSPAD];
    __shared__ float Bs[32][LDSPAD];
    const int n = blockIdx.z;
    const int e0 = blockIdx.x * 64, o0 = blockIdx.y * 64;
    const int t = threadIdx.x;
    const int tx = t & 15, ty = t >> 4;
    const int r = ty * 4, c = tx * 4;
    float acc[4][4] = {};

    const float* xb = x  + (size_t)n * Ech * Dd + (size_t)e0 * Dd;
    const float* wb = lw + (size_t)o0 * Dd;

    for (int kc = 0; kc < 128; kc += 32) {
        #pragma unroll
        for (int p = 0; p < 2; p++) {
            const int idx4 = t + 256 * p;
            const int row  = idx4 >> 3;
            const int k4   = (idx4 & 7) * 4;
            float4 a = *(const float4*)(xb + row * Dd + kc + k4);
            As[k4 + 0][row] = a.x;
            As[k4 + 1][row] = a.y;
            As[k4 + 2][row] = a.z;
            As[k4 + 3][row] = a.w;
            float4 b = *(const float4*)(wb + row * Dd + kc + k4);
            Bs[k4 + 0][row] = b.x;
            Bs[k4 + 1][row] = b.y;
            Bs[k4 + 2][row] = b.z;
            Bs[k4 + 3][row] = b.w;
        }
        __syncthreads();
        micro_fma(As, Bs, r, c, acc);
        __syncthreads();
    }
    float* vb = v + (size_t)n * Ech * Dd + (size_t)e0 * Dd + o0;
    #pragma unroll
    for (int i = 0; i < 4; i++) {
        float4 o;
        o.x = gelu_exact(acc[i][0] + lb[o0 + c + 0]);
        o.y = gelu_exact(acc[i][1] + lb[o0 + c + 1]);
        o.z = gelu_exact(acc[i][2] + lb[o0 + c + 2]);
        o.w = gelu_exact(acc[i][3] + lb[o0 + c + 3]);
        *(float4*)(vb + (size_t)(r + i) * Dd + c) = o;
    }
}

// ---------------------------------------------------------------------------
// k_outgemm: out[n,e,d] = sum_f attn[n,e,f] * v[n,f,d]
// A=attn rows (K contig), B=v [K][N] natural. grid (8,2,128), block 256
// ---------------------------------------------------------------------------
__global__ __launch_bounds__(256) void k_outgemm(
    const float* __restrict__ attn, const float* __restrict__ v,
    float* __restrict__ out)
{
    __shared__ float As[32][LDSPAD];
    __shared__ float Bs[32][LDSPAD];
    const int n = blockIdx.z;
    const int e0 = blockIdx.x * 64, d0 = blockIdx.y * 64;
    const int t = threadIdx.x;
    const int tx = t & 15, ty = t >> 4;
    const int r = ty * 4, c = tx * 4;
    float acc[4][4] = {};

    const float* ab = attn + (size_t)n * Ech * Ech + (size_t)e0 * Ech;
    const float* vb = v    + (size_t)n * Ech * Dd + d0;

    for (int kc = 0; kc < 512; kc += 32) {
        #pragma unroll
        for (int p = 0; p < 2; p++) {
            const int idx4 = t + 256 * p;
            // A: 64 rows x 32 k
            const int arow = idx4 >> 3;
            const int ak4  = (idx4 & 7) * 4;
            float4 a = *(const float4*)(ab + (size_t)arow * Ech + kc + ak4);
            As[ak4 + 0][arow] = a.x;
            As[ak4 + 1][arow] = a.y;
            As[ak4 + 2][arow] = a.z;
            As[ak4 + 3][arow] = a.w;
            // B: 32 rows(f) x 64 d, natural K-major
            const int bk  = idx4 >> 4;           // 16 float4 per row
            const int bd4 = (idx4 & 15) * 4;
            float4 b = *(const float4*)(vb + (size_t)(kc + bk) * Dd + bd4);
            *(float4*)&Bs[bk][bd4] = b;
        }
        __syncthreads();
        micro_fma(As, Bs, r, c, acc);
        __syncthreads();
    }
    float* ob = out + (size_t)n * Ech * Dd + (size_t)e0 * Dd + d0;
    #pragma unroll
    for (int i = 0; i < 4; i++) {
        float4 o = {acc[i][0], acc[i][1], acc[i][2], acc[i][3]};
        *(float4*)(ob + (size_t)(r + i) * Dd + c) = o;
    }
}

// ---------------------------------------------------------------------------
extern "C" void kernel_launch(void* const* d_in, const int* in_sizes, int n_in,
                              void* d_out, int out_size, void* d_ws, size_t ws_size,
                              hipStream_t stream)
{
    const float* x     = (const float*)d_in[0];   // (8,2048,512) == (128,512,128)
    const float* cw    = (const float*)d_in[1];   // (512,4,3)
    const float* cb    = (const float*)d_in[2];   // (512,)
    const float* gamma = (const float*)d_in[3];   // (512,)
    const float* beta  = (const float*)d_in[4];   // (512,)
    const float* lw    = (const float*)d_in[5];   // (128,128)
    const float* lb    = (const float*)d_in[6];   // (128,)

    float* out  = (float*)d_out;                  // 8388608 floats
    float* attn = out + (size_t)8388608;          // 33554432 floats

    float* qpre   = (float*)d_ws;                 // 8388608 floats
    float* kbuf   = qpre + 8388608;               // 8388608 floats
    float* vbuf   = qpre;                         // reuse: q_pre dead after k_qk
    float* csum   = kbuf + 8388608;
    float* csumsq = csum + 512;
    float* scale  = csumsq + 512;
    float* shift  = scale + 512;

    hipMemsetAsync(csum, 0, 2 * 512 * sizeof(float), stream);

    k_conv_gelu_stats<<<dim3(8, 128), 256, 0, stream>>>(x, cw, cb, qpre, csum, csumsq);
    k_stats_final<<<1, 512, 0, stream>>>(csum, csumsq, gamma, beta, scale, shift);
    k_softmax_e_gelu_v2<<<dim3(4, 128), 256, 0, stream>>>(x, kbuf);
    k_qk<<<dim3(8, 8, 128), 256, 0, stream>>>(qpre, scale, shift, kbuf, attn);
    k_rowsoftmax<<<16384, 256, 0, stream>>>(attn);
    k_vgemm<<<dim3(8, 2, 128), 256, 0, stream>>>(x, lw, lb, vbuf);
    k_outgemm<<<dim3(8, 2, 128), 256, 0, stream>>>(attn, vbuf, out);
}

// Round 3
// 342.894 us; speedup vs baseline: 2.1693x; 1.5224x over previous
//
#include <hip/hip_runtime.h>
#include <math.h>

#define Bn   128          // B'
#define Ech  512          // E
#define Dd   128          // D
#define NCNT 16384        // Bn * Dd  (BatchNorm reduction count)

typedef __bf16 bf16;
typedef __attribute__((ext_vector_type(8))) __bf16 bf16x8;
typedef __attribute__((ext_vector_type(4))) __bf16 bf16x4;
typedef __attribute__((ext_vector_type(4))) float f32x4;

__device__ __forceinline__ float gelu_exact(float x) {
    return 0.5f * x * (1.0f + erff(x * 0.70710678118654752f));
}

static __device__ __forceinline__ f32x4 mfma16(bf16x8 a, bf16x8 b, f32x4 c) {
    return __builtin_amdgcn_mfma_f32_16x16x32_bf16(a, b, c, 0, 0, 0);
}

// ---------------------------------------------------------------------------
// LDS tile helpers: [64 rows][128 k] bf16 (16 KB), XOR-swizzled
// byte ^= (row&7)<<4  (applied identically on write and read  — rule #21)
// ---------------------------------------------------------------------------
__device__ __forceinline__ void stage_tile_bf16(const bf16* __restrict__ src,
                                                int src_ld, bf16* __restrict__ lds,
                                                int t)
{
    #pragma unroll
    for (int p = 0; p < 4; p++) {
        const int idx = t + 256 * p;          // 0..1023 16-byte pieces
        const int row = idx >> 4;
        const int k16 = idx & 15;
        const float4 v = *(const float4*)((const char*)src +
                          (size_t)row * src_ld * 2 + k16 * 16);
        const unsigned byte = (unsigned)(row * 256 + k16 * 16) ^ ((row & 7) << 4);
        *(float4*)((char*)lds + byte) = v;
    }
}

__device__ __forceinline__ void stage_tile_f32(const float* __restrict__ src,
                                               int src_ld, bf16* __restrict__ lds,
                                               int t)
{
    #pragma unroll
    for (int p = 0; p < 4; p++) {
        const int idx = t + 256 * p;
        const int row = idx >> 4;
        const int k16 = idx & 15;             // 8 floats -> 8 bf16 (16 B)
        const float4 a = *(const float4*)(src + (size_t)row * src_ld + k16 * 8);
        const float4 b = *(const float4*)(src + (size_t)row * src_ld + k16 * 8 + 4);
        bf16x8 o;
        o[0] = (bf16)a.x; o[1] = (bf16)a.y; o[2] = (bf16)a.z; o[3] = (bf16)a.w;
        o[4] = (bf16)b.x; o[5] = (bf16)b.y; o[6] = (bf16)b.z; o[7] = (bf16)b.w;
        const unsigned byte = (unsigned)(row * 256 + k16 * 16) ^ ((row & 7) << 4);
        *(bf16x8*)((char*)lds + byte) = o;
    }
}

__device__ __forceinline__ bf16x8 frag(const bf16* __restrict__ lds, int row, int koff)
{
    const unsigned byte = (unsigned)(row * 256 + koff * 2) ^ ((row & 7) << 4);
    return *(const bf16x8*)((const char*)lds + byte);
}

// ---------------------------------------------------------------------------
// k1: grouped conv1d (k=3, pad=1, groups=128) + bias + residual + GELU,
//     store q_pre (bf16, pre-BN), accumulate per-channel sum/sumsq (fp32).
// ---------------------------------------------------------------------------
__global__ __launch_bounds__(256) void k_conv_gelu_stats(
    const float* __restrict__ x, const float* __restrict__ cw,
    const float* __restrict__ cb, bf16* __restrict__ qpre,
    float* __restrict__ csum, float* __restrict__ csumsq)
{
    __shared__ float xt[64 * 128];
    const int n  = blockIdx.y;
    const int c0 = blockIdx.x * 64;
    const float* xb = x + (size_t)n * Ech * Dd + (size_t)c0 * Dd;

    const float4* xb4 = (const float4*)xb;
    float4* xt4 = (float4*)xt;
    #pragma unroll
    for (int j = 0; j < 8; j++) xt4[threadIdx.x + 256 * j] = xb4[threadIdx.x + 256 * j];
    __syncthreads();

    const int oloc = threadIdx.x >> 2;
    const int hq   = threadIdx.x & 3;
    const int o    = c0 + oloc;
    const int gb   = oloc & ~3;

    float w[4][3];
    #pragma unroll
    for (int i = 0; i < 4; i++)
        #pragma unroll
        for (int kk = 0; kk < 3; kk++) w[i][kk] = cw[o * 12 + i * 3 + kk];
    const float bias = cb[o];

    float s = 0.f, ss = 0.f;
    bf16* qrow = qpre + (size_t)n * Ech * Dd + (size_t)o * Dd;
    #pragma unroll 4
    for (int j = 0; j < 32; j++) {
        const int h = hq + 4 * j;
        float acc = bias;
        #pragma unroll
        for (int i = 0; i < 4; i++) {
            const float* row = &xt[(gb + i) * 128];
            const float xm = (h > 0)   ? row[h - 1] : 0.f;
            const float xc = row[h];
            const float xp = (h < 127) ? row[h + 1] : 0.f;
            acc = fmaf(xm, w[i][0], acc);
            acc = fmaf(xc, w[i][1], acc);
            acc = fmaf(xp, w[i][2], acc);
        }
        acc += xt[oloc * 128 + h];
        const float g = gelu_exact(acc);
        qrow[h] = (bf16)g;
        s += g; ss = fmaf(g, g, ss);
    }
    s  += __shfl_xor(s, 1);  s  += __shfl_xor(s, 2);
    ss += __shfl_xor(ss, 1); ss += __shfl_xor(ss, 2);
    if (hq == 0) { atomicAdd(&csum[o], s); atomicAdd(&csumsq[o], ss); }
}

// ---------------------------------------------------------------------------
// k2: finalize BN stats -> per-channel scale/shift
// ---------------------------------------------------------------------------
__global__ void k_stats_final(const float* __restrict__ csum,
                              const float* __restrict__ csumsq,
                              const float* __restrict__ gamma,
                              const float* __restrict__ beta,
                              float* __restrict__ scale, float* __restrict__ shift)
{
    const int c = threadIdx.x;
    if (c < Ech) {
        const float mu   = csum[c]   * (1.0f / NCNT);
        const float var  = csumsq[c] * (1.0f / NCNT) - mu * mu;
        const float rstd = rsqrtf(var + 1e-5f);
        const float sc   = gamma[c] * rstd;
        scale[c] = sc;
        shift[c] = beta[c] - mu * sc;
    }
}

// ---------------------------------------------------------------------------
// k3: k = gelu(softmax(x, axis=E)) -> bf16, plus ksum[n][f] = sum_d k  (fp32)
// grid (4,128), block 256. Register-cached single-read-pass.
// ---------------------------------------------------------------------------
__global__ __launch_bounds__(256) void k_softmax_e_gelu_v2(
    const float* __restrict__ x, bf16* __restrict__ kout,
    float* __restrict__ ksum)
{
    __shared__ float4 red[32][8];
    const int n  = blockIdx.y;
    const int qd = blockIdx.x;
    const int t  = threadIdx.x;
    const int d4 = t & 7;
    const int eg = t >> 3;
    const float* xb = x + (size_t)n * Ech * Dd + qd * 32 + d4 * 4;

    float4 vb[16];
    float4 m4 = {-3e38f, -3e38f, -3e38f, -3e38f};
    #pragma unroll
    for (int j = 0; j < 16; j++) {
        const int e = eg + 32 * j;
        float4 v = *(const float4*)(xb + (size_t)e * Dd);
        vb[j] = v;
        m4.x = fmaxf(m4.x, v.x); m4.y = fmaxf(m4.y, v.y);
        m4.z = fmaxf(m4.z, v.z); m4.w = fmaxf(m4.w, v.w);
    }
    red[eg][d4] = m4;
    __syncthreads();
    #pragma unroll
    for (int s = 16; s >= 1; s >>= 1) {
        if (eg < s) {
            float4 a = red[eg][d4], b = red[eg + s][d4];
            a.x = fmaxf(a.x, b.x); a.y = fmaxf(a.y, b.y);
            a.z = fmaxf(a.z, b.z); a.w = fmaxf(a.w, b.w);
            red[eg][d4] = a;
        }
        __syncthreads();
    }
    m4 = red[0][d4];
    __syncthreads();

    float4 s4 = {0.f, 0.f, 0.f, 0.f};
    #pragma unroll
    for (int j = 0; j < 16; j++) {
        float4 v = vb[j];
        v.x = __expf(v.x - m4.x); v.y = __expf(v.y - m4.y);
        v.z = __expf(v.z - m4.z); v.w = __expf(v.w - m4.w);
        vb[j] = v;
        s4.x += v.x; s4.y += v.y; s4.z += v.z; s4.w += v.w;
    }
    red[eg][d4] = s4;
    __syncthreads();
    #pragma unroll
    for (int s = 16; s >= 1; s >>= 1) {
        if (eg < s) {
            float4 a = red[eg][d4], b = red[eg + s][d4];
            a.x += b.x; a.y += b.y; a.z += b.z; a.w += b.w;
            red[eg][d4] = a;
        }
        __syncthreads();
    }
    s4 = red[0][d4];
    const float4 inv4 = {1.0f / s4.x, 1.0f / s4.y, 1.0f / s4.z, 1.0f / s4.w};

    bf16* kb = kout + (size_t)n * Ech * Dd + qd * 32 + d4 * 4;
    #pragma unroll
    for (int j = 0; j < 16; j++) {
        const int e = eg + 32 * j;
        float4 p = vb[j];
        const float g0 = gelu_exact(p.x * inv4.x);
        const float g1 = gelu_exact(p.y * inv4.y);
        const float g2 = gelu_exact(p.z * inv4.z);
        const float g3 = gelu_exact(p.w * inv4.w);
        bf16x4 ov; ov[0] = (bf16)g0; ov[1] = (bf16)g1; ov[2] = (bf16)g2; ov[3] = (bf16)g3;
        *(bf16x4*)(kb + (size_t)e * Dd) = ov;
        // ksum over d: reduce the 8 d4-lanes (adjacent), one atomic per (e, quarter)
        float pp = g0 + g1 + g2 + g3;
        pp += __shfl_xor(pp, 1); pp += __shfl_xor(pp, 2); pp += __shfl_xor(pp, 4);
        if (d4 == 0) atomicAdd(&ksum[n * Ech + e], pp);
    }
}

// ---------------------------------------------------------------------------
// k_qk_mfma: attn_raw[n,e,f] = (sc_e * <qpre_e, k_f> + sh_e * ksum_f) / sqrt(512)
// bf16 MFMA 16x16x32, 64x64 tile per block, K=128 single stage.
// grid (8 e, 8 f, 128 n), block 256 (4 waves, 32x32 quadrants)
// ---------------------------------------------------------------------------
__global__ __launch_bounds__(256) void k_qk_mfma(
    const bf16* __restrict__ qb, const bf16* __restrict__ kbuf,
    const float* __restrict__ scale, const float* __restrict__ shift,
    const float* __restrict__ ksum, float* __restrict__ attn)
{
    __shared__ bf16 As[64 * 128];
    __shared__ bf16 Bs[64 * 128];
    const int n = blockIdx.z, e0 = blockIdx.x * 64, f0 = blockIdx.y * 64;
    const int t = threadIdx.x, lane = t & 63, w = t >> 6;
    const int wr = w >> 1, wc = w & 1;
    const int lr = lane & 15, lg = lane >> 4;

    stage_tile_bf16(qb   + (size_t)n * Ech * Dd + (size_t)e0 * Dd, Dd, As, t);
    stage_tile_bf16(kbuf + (size_t)n * Ech * Dd + (size_t)f0 * Dd, Dd, Bs, t);
    __syncthreads();

    f32x4 acc[2][2] = {};
    #pragma unroll
    for (int ks = 0; ks < 4; ks++) {
        const int ko = ks * 32 + lg * 8;
        const bf16x8 a0 = frag(As, wr * 32 + lr,      ko);
        const bf16x8 a1 = frag(As, wr * 32 + 16 + lr, ko);
        const bf16x8 b0 = frag(Bs, wc * 32 + lr,      ko);
        const bf16x8 b1 = frag(Bs, wc * 32 + 16 + lr, ko);
        acc[0][0] = mfma16(a0, b0, acc[0][0]);
        acc[0][1] = mfma16(a0, b1, acc[0][1]);
        acc[1][0] = mfma16(a1, b0, acc[1][0]);
        acc[1][1] = mfma16(a1, b1, acc[1][1]);
    }

    const float rsc = 0.044194173824159216f;   // 1/sqrt(512)
    float* ab = attn + (size_t)n * Ech * Ech;
    #pragma unroll
    for (int mm = 0; mm < 2; mm++) {
        #pragma unroll
        for (int nn = 0; nn < 2; nn++) {
            const int fcol = f0 + wc * 32 + nn * 16 + lr;
            const float kf = ksum[n * Ech + fcol];
            #pragma unroll
            for (int r4 = 0; r4 < 4; r4++) {
                const int erow = e0 + wr * 32 + mm * 16 + lg * 4 + r4;
                ab[(size_t)erow * Ech + fcol] =
                    fmaf(scale[erow], acc[mm][nn][r4], shift[erow] * kf) * rsc;
            }
        }
    }
}

// ---------------------------------------------------------------------------
// k_rowsoftmax: softmax over last dim (512) of attn, in place.
// ---------------------------------------------------------------------------
__global__ __launch_bounds__(256) void k_rowsoftmax(float* __restrict__ attn)
{
    const int row  = blockIdx.x * 4 + (threadIdx.x >> 6);
    const int lane = threadIdx.x & 63;
    float* rp = attn + (size_t)row * Ech;
    float4 v1 = *(float4*)(rp + lane * 4);
    float4 v2 = *(float4*)(rp + 256 + lane * 4);
    float m = fmaxf(fmaxf(fmaxf(v1.x, v1.y), fmaxf(v1.z, v1.w)),
                    fmaxf(fmaxf(v2.x, v2.y), fmaxf(v2.z, v2.w)));
    #pragma unroll
    for (int off = 32; off >= 1; off >>= 1) m = fmaxf(m, __shfl_xor(m, off));
    v1.x = __expf(v1.x - m); v1.y = __expf(v1.y - m);
    v1.z = __expf(v1.z - m); v1.w = __expf(v1.w - m);
    v2.x = __expf(v2.x - m); v2.y = __expf(v2.y - m);
    v2.z = __expf(v2.z - m); v2.w = __expf(v2.w - m);
    float s = v1.x + v1.y + v1.z + v1.w + v2.x + v2.y + v2.z + v2.w;
    #pragma unroll
    for (int off = 32; off >= 1; off >>= 1) s += __shfl_xor(s, off);
    const float inv = 1.0f / s;
    v1.x *= inv; v1.y *= inv; v1.z *= inv; v1.w *= inv;
    v2.x *= inv; v2.y *= inv; v2.z *= inv; v2.w *= inv;
    *(float4*)(rp + lane * 4) = v1;
    *(float4*)(rp + 256 + lane * 4) = v2;
}

// ---------------------------------------------------------------------------
// k_vgemm_T: vT[n,o,e] = gelu( sum_d lw[o,d]*x[n,e,d] + lb[o] )   (bf16 out)
// A = lw (M=o), B = x rows (N=e), K=128. grid (8 e, 2 o, 128 n), block 256
// ---------------------------------------------------------------------------
__global__ __launch_bounds__(256) void k_vgemm_T(
    const float* __restrict__ x, const float* __restrict__ lw,
    const float* __restrict__ lb, bf16* __restrict__ vT)
{
    __shared__ bf16 As[64 * 128];
    __shared__ bf16 Bs[64 * 128];
    const int n = blockIdx.z, e0 = blockIdx.x * 64, o0 = blockIdx.y * 64;
    const int t = threadIdx.x, lane = t & 63, w = t >> 6;
    const int wr = w >> 1, wc = w & 1;
    const int lr = lane & 15, lg = lane >> 4;

    stage_tile_f32(lw + (size_t)o0 * Dd, Dd, As, t);
    stage_tile_f32(x + (size_t)n * Ech * Dd + (size_t)e0 * Dd, Dd, Bs, t);
    __syncthreads();

    f32x4 acc[2][2] = {};
    #pragma unroll
    for (int ks = 0; ks < 4; ks++) {
        const int ko = ks * 32 + lg * 8;
        const bf16x8 a0 = frag(As, wr * 32 + lr,      ko);
        const bf16x8 a1 = frag(As, wr * 32 + 16 + lr, ko);
        const bf16x8 b0 = frag(Bs, wc * 32 + lr,      ko);
        const bf16x8 b1 = frag(Bs, wc * 32 + 16 + lr, ko);
        acc[0][0] = mfma16(a0, b0, acc[0][0]);
        acc[0][1] = mfma16(a0, b1, acc[0][1]);
        acc[1][0] = mfma16(a1, b0, acc[1][0]);
        acc[1][1] = mfma16(a1, b1, acc[1][1]);
    }

    bf16* vb = vT + (size_t)n * Dd * Ech;
    #pragma unroll
    for (int mm = 0; mm < 2; mm++) {
        #pragma unroll
        for (int nn = 0; nn < 2; nn++) {
            const int ecol = e0 + wc * 32 + nn * 16 + lr;
            #pragma unroll
            for (int r4 = 0; r4 < 4; r4++) {
                const int orow = o0 + wr * 32 + mm * 16 + lg * 4 + r4;
                vb[(size_t)orow * Ech + ecol] =
                    (bf16)gelu_exact(acc[mm][nn][r4] + lb[orow]);
            }
        }
    }
}

// ---------------------------------------------------------------------------
// k_outgemm_mfma: out[n,e,d] = sum_f attn[n,e,f] * vT[n,d,f]
// A = attn rows (fp32->bf16 at stage), B = vT rows. K=512 in 4 chunks.
// grid (8 e, 2 d, 128 n), block 256
// ---------------------------------------------------------------------------
__global__ __launch_bounds__(256) void k_outgemm_mfma(
    const float* __restrict__ attn, const bf16* __restrict__ vT,
    float* __restrict__ out)
{
    __shared__ bf16 As[64 * 128];
    __shared__ bf16 Bs[64 * 128];
    const int n = blockIdx.z, e0 = blockIdx.x * 64, d0 = blockIdx.y * 64;
    const int t = threadIdx.x, lane = t & 63, w = t >> 6;
    const int wr = w >> 1, wc = w & 1;
    const int lr = lane & 15, lg = lane >> 4;

    const float* ab = attn + (size_t)n * Ech * Ech + (size_t)e0 * Ech;
    const bf16*  vb = vT   + (size_t)n * Dd * Ech + (size_t)d0 * Ech;

    f32x4 acc[2][2] = {};
    for (int kc = 0; kc < 512; kc += 128) {
        stage_tile_f32(ab + kc, Ech, As, t);
        stage_tile_bf16(vb + kc, Ech, Bs, t);
        __syncthreads();
        #pragma unroll
        for (int ks = 0; ks < 4; ks++) {
            const int ko = ks * 32 + lg * 8;
            const bf16x8 a0 = frag(As, wr * 32 + lr,      ko);
            const bf16x8 a1 = frag(As, wr * 32 + 16 + lr, ko);
            const bf16x8 b0 = frag(Bs, wc * 32 + lr,      ko);
            const bf16x8 b1 = frag(Bs, wc * 32 + 16 + lr, ko);
            acc[0][0] = mfma16(a0, b0, acc[0][0]);
            acc[0][1] = mfma16(a0, b1, acc[0][1]);
            acc[1][0] = mfma16(a1, b0, acc[1][0]);
            acc[1][1] = mfma16(a1, b1, acc[1][1]);
        }
        __syncthreads();
    }

    float* ob = out + (size_t)n * Ech * Dd;
    #pragma unroll
    for (int mm = 0; mm < 2; mm++) {
        #pragma unroll
        for (int nn = 0; nn < 2; nn++) {
            const int dcol = d0 + wc * 32 + nn * 16 + lr;
            #pragma unroll
            for (int r4 = 0; r4 < 4; r4++) {
                const int erow = e0 + wr * 32 + mm * 16 + lg * 4 + r4;
                ob[(size_t)erow * Dd + dcol] = acc[mm][nn][r4];
            }
        }
    }
}

// ---------------------------------------------------------------------------
extern "C" void kernel_launch(void* const* d_in, const int* in_sizes, int n_in,
                              void* d_out, int out_size, void* d_ws, size_t ws_size,
                              hipStream_t stream)
{
    const float* x     = (const float*)d_in[0];
    const float* cw    = (const float*)d_in[1];
    const float* cb    = (const float*)d_in[2];
    const float* gamma = (const float*)d_in[3];
    const float* beta  = (const float*)d_in[4];
    const float* lw    = (const float*)d_in[5];
    const float* lb    = (const float*)d_in[6];

    float* out  = (float*)d_out;                  // 8,388,608 floats
    float* attn = out + (size_t)8388608;          // 33,554,432 floats

    bf16*  qpre_bf = (bf16*)d_ws;                 // 8,388,608 bf16 (16 MB)
    bf16*  kb_bf   = qpre_bf + 8388608;           // 16 MB
    bf16*  vT_bf   = kb_bf + 8388608;             // 16 MB
    float* ksum    = (float*)(vT_bf + 8388608);   // 65,536 f32
    float* csum    = ksum + 65536;                // 512
    float* csumsq  = csum + 512;
    float* scale   = csumsq + 512;
    float* shift   = scale + 512;

    hipMemsetAsync(ksum, 0, (65536 + 1024) * sizeof(float), stream);

    k_conv_gelu_stats<<<dim3(8, 128), 256, 0, stream>>>(x, cw, cb, qpre_bf, csum, csumsq);
    k_stats_final<<<1, 512, 0, stream>>>(csum, csumsq, gamma, beta, scale, shift);
    k_softmax_e_gelu_v2<<<dim3(4, 128), 256, 0, stream>>>(x, kb_bf, ksum);
    k_qk_mfma<<<dim3(8, 8, 128), 256, 0, stream>>>(qpre_bf, kb_bf, scale, shift, ksum, attn);
    k_rowsoftmax<<<16384, 256, 0, stream>>>(attn);
    k_vgemm_T<<<dim3(8, 2, 128), 256, 0, stream>>>(x, lw, lb, vT_bf);
    k_outgemm_mfma<<<dim3(8, 2, 128), 256, 0, stream>>>(attn, vT_bf, out);
}

// Round 6
// 310.574 us; speedup vs baseline: 2.3951x; 1.1041x over previous
//
#include <hip/hip_runtime.h>
#include <math.h>

#define Bn   128          // B'
#define Ech  512          // E
#define Dd   128          // D
#define NCNT 16384        // Bn * Dd  (BatchNorm reduction count)

typedef __bf16 bf16;
typedef __attribute__((ext_vector_type(8))) __bf16 bf16x8;
typedef __attribute__((ext_vector_type(4))) __bf16 bf16x4;
typedef __attribute__((ext_vector_type(4))) float f32x4;

__device__ __forceinline__ float gelu_exact(float x) {
    return 0.5f * x * (1.0f + erff(x * 0.70710678118654752f));
}

static __device__ __forceinline__ f32x4 mfma16(bf16x8 a, bf16x8 b, f32x4 c) {
    return __builtin_amdgcn_mfma_f32_16x16x32_bf16(a, b, c, 0, 0, 0);
}

// XOR swizzle on byte offsets (same on write and read — rule #21).
// Spreads 8 consecutive rows across 8 distinct 16B slots; 2-way residual
// aliasing (rows r, r+8) is free per m136.
#define SWZ(byte, row) ((unsigned)(byte) ^ (((unsigned)(row) & 7u) << 4))

// ---------------------------------------------------------------------------
// k1: grouped conv1d (k=3, pad=1, groups=128) + bias + residual + GELU,
//     store q_pre (bf16, pre-BN), accumulate per-channel sum/sumsq (fp32).
// ---------------------------------------------------------------------------
__global__ __launch_bounds__(256) void k_conv_gelu_stats(
    const float* __restrict__ x, const float* __restrict__ cw,
    const float* __restrict__ cb, bf16* __restrict__ qpre,
    float* __restrict__ csum, float* __restrict__ csumsq)
{
    __shared__ float xt[64 * 128];
    const int n  = blockIdx.y;
    const int c0 = blockIdx.x * 64;
    const float* xb = x + (size_t)n * Ech * Dd + (size_t)c0 * Dd;

    const float4* xb4 = (const float4*)xb;
    float4* xt4 = (float4*)xt;
    #pragma unroll
    for (int j = 0; j < 8; j++) xt4[threadIdx.x + 256 * j] = xb4[threadIdx.x + 256 * j];
    __syncthreads();

    const int oloc = threadIdx.x >> 2;
    const int hq   = threadIdx.x & 3;
    const int o    = c0 + oloc;
    const int gb   = oloc & ~3;

    float w[4][3];
    #pragma unroll
    for (int i = 0; i < 4; i++)
        #pragma unroll
        for (int kk = 0; kk < 3; kk++) w[i][kk] = cw[o * 12 + i * 3 + kk];
    const float bias = cb[o];

    float s = 0.f, ss = 0.f;
    bf16* qrow = qpre + (size_t)n * Ech * Dd + (size_t)o * Dd;
    #pragma unroll 4
    for (int j = 0; j < 32; j++) {
        const int h = hq + 4 * j;
        float acc = bias;
        #pragma unroll
        for (int i = 0; i < 4; i++) {
            const float* row = &xt[(gb + i) * 128];
            const float xm = (h > 0)   ? row[h - 1] : 0.f;
            const float xc = row[h];
            const float xp = (h < 127) ? row[h + 1] : 0.f;
            acc = fmaf(xm, w[i][0], acc);
            acc = fmaf(xc, w[i][1], acc);
            acc = fmaf(xp, w[i][2], acc);
        }
        acc += xt[oloc * 128 + h];
        const float g = gelu_exact(acc);
        qrow[h] = (bf16)g;
        s += g; ss = fmaf(g, g, ss);
    }
    s  += __shfl_xor(s, 1);  s  += __shfl_xor(s, 2);
    ss += __shfl_xor(ss, 1); ss += __shfl_xor(ss, 2);
    if (hq == 0) { atomicAdd(&csum[o], s); atomicAdd(&csumsq[o], ss); }
}

// ---------------------------------------------------------------------------
// k2: finalize BN stats -> per-channel scale/shift
// ---------------------------------------------------------------------------
__global__ void k_stats_final(const float* __restrict__ csum,
                              const float* __restrict__ csumsq,
                              const float* __restrict__ gamma,
                              const float* __restrict__ beta,
                              float* __restrict__ scale, float* __restrict__ shift)
{
    const int c = threadIdx.x;
    if (c < Ech) {
        const float mu   = csum[c]   * (1.0f / NCNT);
        const float var  = csumsq[c] * (1.0f / NCNT) - mu * mu;
        const float rstd = rsqrtf(var + 1e-5f);
        const float sc   = gamma[c] * rstd;
        scale[c] = sc;
        shift[c] = beta[c] - mu * sc;
    }
}

// ---------------------------------------------------------------------------
// k3: k = gelu(softmax(x, axis=E)) -> bf16. Register-cached single-pass.
// grid (4,128), block 256.
// ---------------------------------------------------------------------------
__global__ __launch_bounds__(256) void k_softmax_e_gelu_v2(
    const float* __restrict__ x, bf16* __restrict__ kout)
{
    __shared__ float4 red[32][8];
    const int n  = blockIdx.y;
    const int qd = blockIdx.x;
    const int t  = threadIdx.x;
    const int d4 = t & 7;
    const int eg = t >> 3;
    const float* xb = x + (size_t)n * Ech * Dd + qd * 32 + d4 * 4;

    float4 vb[16];
    float4 m4 = {-3e38f, -3e38f, -3e38f, -3e38f};
    #pragma unroll
    for (int j = 0; j < 16; j++) {
        const int e = eg + 32 * j;
        float4 v = *(const float4*)(xb + (size_t)e * Dd);
        vb[j] = v;
        m4.x = fmaxf(m4.x, v.x); m4.y = fmaxf(m4.y, v.y);
        m4.z = fmaxf(m4.z, v.z); m4.w = fmaxf(m4.w, v.w);
    }
    red[eg][d4] = m4;
    __syncthreads();
    #pragma unroll
    for (int s = 16; s >= 1; s >>= 1) {
        if (eg < s) {
            float4 a = red[eg][d4], b = red[eg + s][d4];
            a.x = fmaxf(a.x, b.x); a.y = fmaxf(a.y, b.y);
            a.z = fmaxf(a.z, b.z); a.w = fmaxf(a.w, b.w);
            red[eg][d4] = a;
        }
        __syncthreads();
    }
    m4 = red[0][d4];
    __syncthreads();

    float4 s4 = {0.f, 0.f, 0.f, 0.f};
    #pragma unroll
    for (int j = 0; j < 16; j++) {
        float4 v = vb[j];
        v.x = __expf(v.x - m4.x); v.y = __expf(v.y - m4.y);
        v.z = __expf(v.z - m4.z); v.w = __expf(v.w - m4.w);
        vb[j] = v;
        s4.x += v.x; s4.y += v.y; s4.z += v.z; s4.w += v.w;
    }
    red[eg][d4] = s4;
    __syncthreads();
    #pragma unroll
    for (int s = 16; s >= 1; s >>= 1) {
        if (eg < s) {
            float4 a = red[eg][d4], b = red[eg + s][d4];
            a.x += b.x; a.y += b.y; a.z += b.z; a.w += b.w;
            red[eg][d4] = a;
        }
        __syncthreads();
    }
    s4 = red[0][d4];
    const float4 inv4 = {1.0f / s4.x, 1.0f / s4.y, 1.0f / s4.z, 1.0f / s4.w};

    bf16* kb = kout + (size_t)n * Ech * Dd + qd * 32 + d4 * 4;
    #pragma unroll
    for (int j = 0; j < 16; j++) {
        const int e = eg + 32 * j;
        float4 p = vb[j];
        bf16x4 ov;
        ov[0] = (bf16)gelu_exact(p.x * inv4.x);
        ov[1] = (bf16)gelu_exact(p.y * inv4.y);
        ov[2] = (bf16)gelu_exact(p.z * inv4.z);
        ov[3] = (bf16)gelu_exact(p.w * inv4.w);
        *(bf16x4*)(kb + (size_t)e * Dd) = ov;
    }
}

// ---------------------------------------------------------------------------
// k_vgemm_T: vT[n,o,e] = gelu( sum_d lw[o,d]*x[n,e,d] + lb[o] )   (bf16 out)
// grid (8 e, 2 o, 128 n), block 256. 64x64 tile, [64][128] swizzled LDS.
// ---------------------------------------------------------------------------
__global__ __launch_bounds__(256) void k_vgemm_T(
    const float* __restrict__ x, const float* __restrict__ lw,
    const float* __restrict__ lb, bf16* __restrict__ vT)
{
    __shared__ bf16 As[64 * 128];
    __shared__ bf16 Bs[64 * 128];
    const int n = blockIdx.z, e0 = blockIdx.x * 64, o0 = blockIdx.y * 64;
    const int t = threadIdx.x, lane = t & 63, w = t >> 6;
    const int wr = w >> 1, wc = w & 1;
    const int lr = lane & 15, lg = lane >> 4;

    // stage (f32 -> bf16, swizzled)
    {
        const float* sa = lw + (size_t)o0 * Dd;
        const float* sb = x + (size_t)n * Ech * Dd + (size_t)e0 * Dd;
        #pragma unroll
        for (int p = 0; p < 4; p++) {
            const int idx = t + 256 * p;
            const int row = idx >> 4, k16 = idx & 15;
            float4 a0 = *(const float4*)(sa + (size_t)row * Dd + k16 * 8);
            float4 a1 = *(const float4*)(sa + (size_t)row * Dd + k16 * 8 + 4);
            bf16x8 oa;
            oa[0]=(bf16)a0.x; oa[1]=(bf16)a0.y; oa[2]=(bf16)a0.z; oa[3]=(bf16)a0.w;
            oa[4]=(bf16)a1.x; oa[5]=(bf16)a1.y; oa[6]=(bf16)a1.z; oa[7]=(bf16)a1.w;
            *(bf16x8*)((char*)As + SWZ(row * 256 + k16 * 16, row)) = oa;
            float4 b0 = *(const float4*)(sb + (size_t)row * Dd + k16 * 8);
            float4 b1 = *(const float4*)(sb + (size_t)row * Dd + k16 * 8 + 4);
            bf16x8 ob;
            ob[0]=(bf16)b0.x; ob[1]=(bf16)b0.y; ob[2]=(bf16)b0.z; ob[3]=(bf16)b0.w;
            ob[4]=(bf16)b1.x; ob[5]=(bf16)b1.y; ob[6]=(bf16)b1.z; ob[7]=(bf16)b1.w;
            *(bf16x8*)((char*)Bs + SWZ(row * 256 + k16 * 16, row)) = ob;
        }
    }
    __syncthreads();

    f32x4 acc[2][2] = {};
    #pragma unroll
    for (int ks = 0; ks < 4; ks++) {
        const int ko = ks * 32 + lg * 8;
        const int ra0 = wr * 32 + lr, ra1 = wr * 32 + 16 + lr;
        const int rb0 = wc * 32 + lr, rb1 = wc * 32 + 16 + lr;
        const bf16x8 a0 = *(const bf16x8*)((char*)As + SWZ(ra0 * 256 + ko * 2, ra0));
        const bf16x8 a1 = *(const bf16x8*)((char*)As + SWZ(ra1 * 256 + ko * 2, ra1));
        const bf16x8 b0 = *(const bf16x8*)((char*)Bs + SWZ(rb0 * 256 + ko * 2, rb0));
        const bf16x8 b1 = *(const bf16x8*)((char*)Bs + SWZ(rb1 * 256 + ko * 2, rb1));
        acc[0][0] = mfma16(a0, b0, acc[0][0]);
        acc[0][1] = mfma16(a0, b1, acc[0][1]);
        acc[1][0] = mfma16(a1, b0, acc[1][0]);
        acc[1][1] = mfma16(a1, b1, acc[1][1]);
    }

    bf16* vb = vT + (size_t)n * Dd * Ech;
    #pragma unroll
    for (int mm = 0; mm < 2; mm++) {
        #pragma unroll
        for (int nn = 0; nn < 2; nn++) {
            const int ecol = e0 + wc * 32 + nn * 16 + lr;
            #pragma unroll
            for (int r4 = 0; r4 < 4; r4++) {
                const int orow = o0 + wr * 32 + mm * 16 + lg * 4 + r4;
                vb[(size_t)orow * Ech + ecol] =
                    (bf16)gelu_exact(acc[mm][nn][r4] + lb[orow]);
            }
        }
    }
}

// ---------------------------------------------------------------------------
// k_attn_fused: flash-style  S = q'k^T/sqrt(512) -> row-softmax -> attn out,
//               then out = P V, all in one block per (n, 64-row e-strip).
// BN folded into Q staging: q' = scale[e]*qpre + shift[e]  (== BN(q)).
// LDS (STATIC 144 KB — validated at compile time vs gfx950's 160 KB/CU):
//      [0,16K) Q 64x128 bf16 | [16K,144K) K 512x128 bf16
//      after QK: [16K,80K) P 64x512 bf16 | [80K,144K) V-chunk 128x256 bf16
// grid (8, 128), block 256 (4 waves; wave w owns rows w*16..w*16+15).
// ---------------------------------------------------------------------------
#define QS_OFF 0
#define KS_OFF 16384
#define PS_OFF 16384
#define VS_OFF 81920
#define LDS_TOTAL 147456

__global__ __launch_bounds__(256) void k_attn_fused(
    const bf16* __restrict__ qpre, const bf16* __restrict__ kbuf,
    const bf16* __restrict__ vT, const float* __restrict__ scale,
    const float* __restrict__ shift, float* __restrict__ attn,
    float* __restrict__ out)
{
    __shared__ char lds[LDS_TOTAL];
    const int n = blockIdx.y, e0 = blockIdx.x * 64;
    const int t = threadIdx.x, lane = t & 63, w = t >> 6;
    const int lr = lane & 15, lg = lane >> 4;

    // ---- stage Q (BN applied) 64x128 ----
    {
        const bf16* src = qpre + (size_t)n * Ech * Dd + (size_t)e0 * Dd;
        #pragma unroll
        for (int p = 0; p < 4; p++) {
            const int idx = t + 256 * p;
            const int row = idx >> 4, k16 = idx & 15;
            bf16x8 v = *(const bf16x8*)(src + row * Dd + k16 * 8);
            const float sc = scale[e0 + row], sh = shift[e0 + row];
            bf16x8 o;
            #pragma unroll
            for (int j = 0; j < 8; j++) o[j] = (bf16)fmaf((float)v[j], sc, sh);
            *(bf16x8*)(lds + QS_OFF + SWZ(row * 256 + k16 * 16, row)) = o;
        }
    }
    // ---- stage K panel 512x128 ----
    {
        const bf16* src = kbuf + (size_t)n * Ech * Dd;
        #pragma unroll
        for (int p = 0; p < 32; p++) {
            const int idx = t + 256 * p;
            const int row = idx >> 4, k16 = idx & 15;
            float4 v = *(const float4*)(src + row * Dd + k16 * 8);
            *(float4*)(lds + KS_OFF + SWZ(row * 256 + k16 * 16, row)) = v;
        }
    }
    __syncthreads();

    // ---- QK: wave w rows [w*16, w*16+16), all 512 cols ----
    f32x4 acc[32];
    #pragma unroll
    for (int i = 0; i < 32; i++) acc[i] = (f32x4){0.f, 0.f, 0.f, 0.f};
    #pragma unroll
    for (int ks = 0; ks < 4; ks++) {
        const int arow = w * 16 + lr;
        const int ko = ks * 32 + lg * 8;
        const bf16x8 a = *(const bf16x8*)(lds + QS_OFF + SWZ(arow * 256 + ko * 2, arow));
        #pragma unroll
        for (int ft = 0; ft < 32; ft++) {
            const int brow = ft * 16 + lr;
            const bf16x8 b = *(const bf16x8*)(lds + KS_OFF + SWZ(brow * 256 + ko * 2, brow));
            acc[ft] = mfma16(a, b, acc[ft]);
        }
    }
    __syncthreads();   // everyone done reading Q/K; region becomes P/V

    // ---- in-register row softmax (rows: e = e0 + w*16 + lg*4 + r4) ----
    const float rsc = 0.044194173824159216f;   // 1/sqrt(512)
    float m[4] = {-3e38f, -3e38f, -3e38f, -3e38f};
    #pragma unroll
    for (int ft = 0; ft < 32; ft++)
        #pragma unroll
        for (int r4 = 0; r4 < 4; r4++) m[r4] = fmaxf(m[r4], acc[ft][r4]);
    #pragma unroll
    for (int off = 1; off <= 8; off <<= 1)
        #pragma unroll
        for (int r4 = 0; r4 < 4; r4++) m[r4] = fmaxf(m[r4], __shfl_xor(m[r4], off));

    float s[4] = {0.f, 0.f, 0.f, 0.f};
    #pragma unroll
    for (int ft = 0; ft < 32; ft++)
        #pragma unroll
        for (int r4 = 0; r4 < 4; r4++) {
            const float p = __expf((acc[ft][r4] - m[r4]) * rsc);
            acc[ft][r4] = p;
            s[r4] += p;
        }
    #pragma unroll
    for (int off = 1; off <= 8; off <<= 1)
        #pragma unroll
        for (int r4 = 0; r4 < 4; r4++) s[r4] += __shfl_xor(s[r4], off);
    float inv[4];
    #pragma unroll
    for (int r4 = 0; r4 < 4; r4++) inv[r4] = 1.0f / s[r4];

    // ---- write P (bf16) to LDS, rows 1024 B, swizzled ----
    #pragma unroll
    for (int ft = 0; ft < 32; ft++)
        #pragma unroll
        for (int r4 = 0; r4 < 4; r4++) {
            const int row = w * 16 + lg * 4 + r4;
            const int col = ft * 16 + lr;
            *(bf16*)(lds + PS_OFF + SWZ(row * 1024 + col * 2, row)) =
                (bf16)(acc[ft][r4] * inv[r4]);
        }

    // ---- stage V chunk 0 (f 0..255): 128 rows x 512 B ----
    const bf16* vsrc = vT + (size_t)n * Dd * Ech;
    #pragma unroll
    for (int p = 0; p < 16; p++) {
        const int idx = t + 256 * p;
        const int row = idx >> 5, c16 = idx & 31;
        float4 v = *(const float4*)(vsrc + (size_t)row * Ech + c16 * 8);
        *(float4*)(lds + VS_OFF + SWZ(row * 512 + c16 * 16, row)) = v;
    }
    __syncthreads();   // P + V0 ready

    // ---- PV chunk 0 ----
    f32x4 acc2[8];
    #pragma unroll
    for (int i = 0; i < 8; i++) acc2[i] = (f32x4){0.f, 0.f, 0.f, 0.f};
    #pragma unroll
    for (int kf = 0; kf < 8; kf++) {
        const int arow = w * 16 + lr;
        const int fcol = kf * 32 + lg * 8;
        const bf16x8 a = *(const bf16x8*)(lds + PS_OFF + SWZ(arow * 1024 + fcol * 2, arow));
        #pragma unroll
        for (int dt = 0; dt < 8; dt++) {
            const int brow = dt * 16 + lr;
            const bf16x8 b = *(const bf16x8*)(lds + VS_OFF + SWZ(brow * 512 + fcol * 2, brow));
            acc2[dt] = mfma16(a, b, acc2[dt]);
        }
    }

    // ---- write attn (f32) from P LDS, coalesced ----
    {
        float* ab = attn + (size_t)n * Ech * Ech + (size_t)e0 * Ech;
        #pragma unroll
        for (int p = 0; p < 32; p++) {
            const int idx = t + 256 * p;           // float4 units: 64 rows x 128
            const int row = idx >> 7, c4 = idx & 127;
            bf16x4 pv = *(const bf16x4*)(lds + PS_OFF + SWZ(row * 1024 + c4 * 8, row));
            float4 o = {(float)pv[0], (float)pv[1], (float)pv[2], (float)pv[3]};
            *(float4*)(ab + (size_t)row * Ech + c4 * 4) = o;
        }
    }
    __syncthreads();   // all PV-chunk0 reads + attn reads done

    // ---- stage V chunk 1 (f 256..511) ----
    #pragma unroll
    for (int p = 0; p < 16; p++) {
        const int idx = t + 256 * p;
        const int row = idx >> 5, c16 = idx & 31;
        float4 v = *(const float4*)(vsrc + (size_t)row * Ech + 256 + c16 * 8);
        *(float4*)(lds + VS_OFF + SWZ(row * 512 + c16 * 16, row)) = v;
    }
    __syncthreads();

    // ---- PV chunk 1 ----
    #pragma unroll
    for (int kf = 0; kf < 8; kf++) {
        const int arow = w * 16 + lr;
        const int fcol = 256 + kf * 32 + lg * 8;
        const bf16x8 a = *(const bf16x8*)(lds + PS_OFF + SWZ(arow * 1024 + fcol * 2, arow));
        #pragma unroll
        for (int dt = 0; dt < 8; dt++) {
            const int brow = dt * 16 + lr;
            const int vcol = kf * 32 + lg * 8;
            const bf16x8 b = *(const bf16x8*)(lds + VS_OFF + SWZ(brow * 512 + vcol * 2, brow));
            acc2[dt] = mfma16(a, b, acc2[dt]);
        }
    }

    // ---- write out ----
    float* ob = out + (size_t)n * Ech * Dd;
    #pragma unroll
    for (int dt = 0; dt < 8; dt++)
        #pragma unroll
        for (int r4 = 0; r4 < 4; r4++) {
            const int erow = e0 + w * 16 + lg * 4 + r4;
            const int dcol = dt * 16 + lr;
            ob[(size_t)erow * Dd + dcol] = acc2[dt][r4];
        }
}

// ---------------------------------------------------------------------------
extern "C" void kernel_launch(void* const* d_in, const int* in_sizes, int n_in,
                              void* d_out, int out_size, void* d_ws, size_t ws_size,
                              hipStream_t stream)
{
    const float* x     = (const float*)d_in[0];
    const float* cw    = (const float*)d_in[1];
    const float* cb    = (const float*)d_in[2];
    const float* gamma = (const float*)d_in[3];
    const float* beta  = (const float*)d_in[4];
    const float* lw    = (const float*)d_in[5];
    const float* lb    = (const float*)d_in[6];

    float* out  = (float*)d_out;                  // 8,388,608 floats
    float* attn = out + (size_t)8388608;          // 33,554,432 floats

    bf16*  qpre_bf = (bf16*)d_ws;                 // 16 MB
    bf16*  kb_bf   = qpre_bf + 8388608;           // 16 MB
    bf16*  vT_bf   = kb_bf + 8388608;             // 16 MB
    float* csum    = (float*)(vT_bf + 8388608);   // 512
    float* csumsq  = csum + 512;
    float* scale   = csumsq + 512;
    float* shift   = scale + 512;

    hipMemsetAsync(csum, 0, 2 * 512 * sizeof(float), stream);

    k_conv_gelu_stats<<<dim3(8, 128), 256, 0, stream>>>(x, cw, cb, qpre_bf, csum, csumsq);
    k_stats_final<<<1, 512, 0, stream>>>(csum, csumsq, gamma, beta, scale, shift);
    k_softmax_e_gelu_v2<<<dim3(4, 128), 256, 0, stream>>>(x, kb_bf);
    k_vgemm_T<<<dim3(8, 2, 128), 256, 0, stream>>>(x, lw, lb, vT_bf);
    k_attn_fused<<<dim3(8, 128), 256, 0, stream>>>(
        qpre_bf, kb_bf, vT_bf, scale, shift, attn, out);
}